// Round 1
// 278.011 us; speedup vs baseline: 1.0245x; 1.0245x over previous
//
#include <hip/hip_runtime.h>
#include <stdint.h>

#define BN 4
#define SN 4096
#define EN 256
#define PN 32
#define FN 1024
#define BS (BN*SN)   // 16384
#define PAUG 64      // 32 xs chans + aug (+ zero pad to 64)

typedef uint16_t bf16_t;
typedef short v4s  __attribute__((ext_vector_type(4)));
typedef short v8s  __attribute__((ext_vector_type(8)));
typedef __bf16 bf16x8 __attribute__((ext_vector_type(8)));
typedef float v4f   __attribute__((ext_vector_type(4)));
typedef float v16f  __attribute__((ext_vector_type(16)));

#define MFMA16(a,b,c) __builtin_amdgcn_mfma_f32_16x16x32_bf16(a,b,c,0,0,0)
#define MFMA32(a,b,c) __builtin_amdgcn_mfma_f32_32x32x16_bf16(a,b,c,0,0,0)

__device__ __forceinline__ float b2f(bf16_t x){
    uint32_t u = ((uint32_t)x) << 16; float f; __builtin_memcpy(&f, &u, 4); return f;
}
__device__ __forceinline__ bf16_t f2b(float f){
    uint32_t u; __builtin_memcpy(&u, &f, 4);
    u += 0x7FFFu + ((u >> 16) & 1u);           // RNE
    return (bf16_t)(u >> 16);
}
__device__ __forceinline__ bf16x8 ldb8(const bf16_t* p){
    v8s r = *(const v8s*)p; return __builtin_bit_cast(bf16x8, r);
}
// 8-B-aligned load pair (for LDS rows with odd 8-B stride -> 2-way-free banks)
__device__ __forceinline__ bf16x8 ldb8u(const bf16_t* p){
    v4s lo = *(const v4s*)p;
    v4s hi = *(const v4s*)(p + 4);
    v8s r = __builtin_shufflevector(lo, hi, 0,1,2,3,4,5,6,7);
    return __builtin_bit_cast(bf16x8, r);
}
__device__ __forceinline__ float ldsc(const float* p){ return *p; }
__device__ __forceinline__ float ldsc(const bf16_t* p){ return b2f(*p); }
__device__ __forceinline__ void stsc(float* p, float v){ *p = v; }
__device__ __forceinline__ void stsc(bf16_t* p, float v){ *p = f2b(v); }

#if __has_builtin(__builtin_amdgcn_cvt_pk_bf16_f32)
typedef __bf16 bf16x2 __attribute__((ext_vector_type(2)));
__device__ __forceinline__ uint32_t pkbf16(float a, float b){
    bf16x2 r = __builtin_amdgcn_cvt_pk_bf16_f32(a, b);
    return __builtin_bit_cast(uint32_t, r);
}
#else
__device__ __forceinline__ uint32_t pkbf16(float a, float b){
    return (uint32_t)f2b(a) | ((uint32_t)f2b(b) << 16);
}
#endif

typedef const __attribute__((address_space(1))) uint32_t* glds_gp;
typedef __attribute__((address_space(3))) uint32_t* glds_lp;
__device__ __forceinline__ void glds16(const bf16_t* g, bf16_t* l){
    __builtin_amdgcn_global_load_lds((glds_gp)g, (glds_lp)l, 16, 0, 0);
}

// ---------------------------------------------------------------------------
// prep: (a) src fp32->bf16, (b) 4 weight cvts, (c) posxs. One launch.
// ---------------------------------------------------------------------------
__global__ __launch_bounds__(256) void prep_kernel(
    const float* __restrict__ src, bf16_t* __restrict__ srcb,
    const float* __restrict__ Wv, bf16_t* __restrict__ Wvb,
    const float* __restrict__ Wo, bf16_t* __restrict__ Wob,
    const float* __restrict__ W1, bf16_t* __restrict__ W1b,
    const float* __restrict__ W2, bf16_t* __restrict__ W2b,
    const float* __restrict__ pos, const float* __restrict__ Wp,
    const float* __restrict__ bp,  const float* __restrict__ lsp,
    bf16_t* __restrict__ xk, bf16_t* __restrict__ xq)
{
    __shared__ float Wsh[PN*PN];
    __shared__ float bsh[PN];
    int bid = blockIdx.x;
    int tid = threadIdx.x;

    if (bid < 4736){
        const float* sp; bf16_t* dp; int off;
        if (bid < 4096){ sp = src; dp = srcb; off = (bid*256 + tid)*4; }
        else {
            int i = ((bid - 4096)*256 + tid)*4;
            if      (i <  65536){ sp=Wv; dp=Wvb; off=i; }
            else if (i < 131072){ sp=Wo; dp=Wob; off=i- 65536; }
            else if (i < 393216){ sp=W1; dp=W1b; off=i-131072; }
            else                { sp=W2; dp=W2b; off=i-393216; }
        }
        float4 f = *(const float4*)(sp + off);
        v4s o;
        o.x = (short)f2b(f.x); o.y = (short)f2b(f.y);
        o.z = (short)f2b(f.z); o.w = (short)f2b(f.w);
        *(v4s*)(dp + off) = o;
        return;
    }

    int pb = bid - 4736;          // 0..63
    int b  = pb >> 4;
    int s  = (pb & 15)*256 + tid;

    for (int i = tid; i < PN*PN; i += 256) Wsh[i] = Wp[i];
    if (tid < PN) bsh[tid] = bp[tid];
    __syncthreads();

    float inv_ls = 1.0f / lsp[0];
    const float c1f = 1.4426950408889634f;

    float col[PN];
    #pragma unroll
    for (int p = 0; p < PN; p++) col[p] = pos[((size_t)b*PN + p)*SN + s];

    uint16_t xb[PN], qb[PN];
    float sq = 0.f;
    #pragma unroll 4
    for (int o = 0; o < PN; o++){
        float pe = bsh[o];
        #pragma unroll
        for (int p = 0; p < PN; p++) pe += col[p] * Wsh[o*PN + p];
        float pv = pe * inv_ls;
        uint16_t h = f2b(pv);
        xb[o] = h;
        qb[o] = f2b(c1f * pv);
        float xr = b2f(h);
        sq += xr * xr;
    }

    size_t base = ((size_t)b*SN + s) * PAUG;
    v8s pk[8];
    #pragma unroll
    for (int c = 0; c < 4; c++)
        #pragma unroll
        for (int j = 0; j < 8; j++) ((short*)&pk[c])[j] = (short)xb[c*8 + j];
    #pragma unroll
    for (int c = 4; c < 8; c++)
        #pragma unroll
        for (int j = 0; j < 8; j++) ((short*)&pk[c])[j] = 0;
    ((short*)&pk[4])[0] = (short)f2b(-0.5f * sq);
    ((short*)&pk[4])[1] = (short)0x3F80;   // 1.0
    #pragma unroll
    for (int c = 0; c < 8; c++) *(v8s*)(xk + base + c*8) = pk[c];

    #pragma unroll
    for (int c = 0; c < 4; c++)
        #pragma unroll
        for (int j = 0; j < 8; j++) ((short*)&pk[c])[j] = (short)qb[c*8 + j];
    ((short*)&pk[4])[0] = (short)f2b(c1f);
    ((short*)&pk[4])[1] = (short)f2b(-0.5f * sq * c1f);
    #pragma unroll
    for (int c = 0; c < 8; c++) *(v8s*)(xq + base + c*8) = pk[c];
}

// ---------------------------------------------------------------------------
// gemm_t: out = A @ W^T (+bias, opt relu). Block 64m x 64n, 4 waves on m.
// BOTH A and W tiles staged via global_load_lds in 64k chunks, double-buffered
// (32 KB LDS). XOR piece-swizzle folded into the per-lane SOURCE address so
// LDS rows are 128 B and all b128 fragment reads are 2-way (free).
// EPI 0: bias ; 1: relu ; 3: bias -> transposed store vt[b][e][s]
// ---------------------------------------------------------------------------
template<int EPI, typename OutT>
__global__ __launch_bounds__(256) void gemm_t(
    const bf16_t* __restrict__ A, const bf16_t* __restrict__ W,
    const float* __restrict__ bias, OutT* __restrict__ out,
    bf16_t* __restrict__ vt, int N, int K)
{
    __shared__ __align__(16) bf16_t At[2][4096];   // 2 x 8 KB
    __shared__ __align__(16) bf16_t Wt[2][4096];   // 2 x 8 KB
    int tid = threadIdx.x;
    int lane = tid & 63, wv = tid >> 6, col = lane & 15, quad = lane >> 4;
    int m0 = blockIdx.x * 64, n0 = blockIdx.y * 64;
    int nck = K >> 6;

    int srow = tid >> 3;                      // 0..31
    int spc  = (tid & 7) ^ (srow & 7);        // swizzled source piece
    const bf16_t* asrc = A + (size_t)(m0 + srow)*K + spc*8;
    const bf16_t* wsrc = W + (size_t)(n0 + srow)*K + spc*8;

    v4f acc[4];
    #pragma unroll
    for (int t = 0; t < 4; t++) acc[t] = (v4f){0.f,0.f,0.f,0.f};

    // stage chunk 0
    glds16(asrc, &At[0][tid*8]);
    glds16(asrc + (size_t)32*K, &At[0][2048 + tid*8]);
    glds16(wsrc, &Wt[0][tid*8]);
    glds16(wsrc + (size_t)32*K, &Wt[0][2048 + tid*8]);
    __syncthreads();

    for (int c = 0; c < nck; c++){
        int cb = c & 1;
        if (c + 1 < nck){
            glds16(asrc + (c+1)*64, &At[cb^1][tid*8]);
            glds16(asrc + (size_t)32*K + (c+1)*64, &At[cb^1][2048 + tid*8]);
            glds16(wsrc + (c+1)*64, &Wt[cb^1][tid*8]);
            glds16(wsrc + (size_t)32*K + (c+1)*64, &Wt[cb^1][2048 + tid*8]);
        }
        #pragma unroll
        for (int kc = 0; kc < 2; kc++){
            int pc = ((kc*4 + quad) ^ (col & 7)) * 8;
            bf16x8 a = ldb8(&At[cb][(wv*16 + col)*64 + pc]);
            #pragma unroll
            for (int t = 0; t < 4; t++){
                bf16x8 b = ldb8(&Wt[cb][(t*16 + col)*64 + pc]);
                acc[t] = MFMA16(a, b, acc[t]);
            }
        }
        __syncthreads();
    }

    float bfv[4];
    #pragma unroll
    for (int t = 0; t < 4; t++) bfv[t] = bias[n0 + t*16 + col];

    if constexpr (EPI == 3){
        __shared__ uint16_t Tsh[64*74];
        #pragma unroll
        for (int r = 0; r < 4; r++)
            #pragma unroll
            for (int t = 0; t < 4; t++)
                Tsh[(wv*16 + quad*4 + r)*74 + t*16 + col] = f2b(acc[t][r] + bfv[t]);
        __syncthreads();
        int e = tid >> 2, sc = tid & 3;
        int b = m0 >> 12;
        int sl = (m0 & (SN-1)) + sc*16;
        v8s p0, p1;
        #pragma unroll
        for (int i = 0; i < 8; i++) ((short*)&p0)[i] = (short)Tsh[(sc*16 + i)*74 + e];
        #pragma unroll
        for (int i = 0; i < 8; i++) ((short*)&p1)[i] = (short)Tsh[(sc*16 + 8 + i)*74 + e];
        bf16_t* dst = vt + ((size_t)b*EN + n0 + e)*SN + sl;
        *(v8s*)dst = p0;
        *(v8s*)(dst + 8) = p1;
    } else {
        #pragma unroll
        for (int r = 0; r < 4; r++){
            int row = m0 + wv*16 + quad*4 + r;
            #pragma unroll
            for (int t = 0; t < 4; t++){
                float y = acc[t][r] + bfv[t];
                if constexpr (EPI == 1) y = fmaxf(y, 0.f);
                stsc(out + (size_t)row*N + n0 + t*16 + col, y);
            }
        }
    }
}

// ---------------------------------------------------------------------------
// ln_kernel: out = LayerNorm(y + res) * gamma + beta.  32 rows/block.
// ---------------------------------------------------------------------------
template<typename OutT, typename ResT>
__global__ __launch_bounds__(256) void ln_kernel(
    const bf16_t* __restrict__ y, const ResT* __restrict__ res,
    const float* __restrict__ gamma, const float* __restrict__ beta,
    OutT* __restrict__ out)
{
    int tid = threadIdx.x;
    int row = blockIdx.x * 32 + (tid >> 3);
    int l8  = tid & 7;
    size_t base = (size_t)row * EN;
    float v[32];
    float s1 = 0.f, s2 = 0.f;
    #pragma unroll
    for (int i = 0; i < 4; i++){
        int off = l8*8 + i*64;
        v8s a = *(const v8s*)(y + base + off);
        #pragma unroll
        for (int j = 0; j < 8; j++){
            float t = b2f((bf16_t)(uint16_t)a[j]) + ldsc(res + base + off + j);
            v[i*8 + j] = t; s1 += t; s2 += t*t;
        }
    }
    #pragma unroll
    for (int m = 1; m <= 4; m <<= 1){
        s1 += __shfl_xor(s1, m);
        s2 += __shfl_xor(s2, m);
    }
    float mu = s1 * (1.f/256.f);
    float rs = rsqrtf(s2 * (1.f/256.f) - mu*mu + 1e-5f);
    #pragma unroll
    for (int i = 0; i < 4; i++){
        int off = l8*8 + i*64;
        #pragma unroll
        for (int j = 0; j < 8; j++)
            stsc(out + base + off + j, (v[i*8+j]-mu)*rs*gamma[off+j] + beta[off+j]);
    }
}

// ---------------------------------------------------------------------------
// Attention round 10: Q=32/block, grid 512, 8 waves (512 thr) per block.
// Chunk = 128 keys, 32 chunks, single-buffered Vl (64 KB) -> 2 blocks/CU =
// 16 waves/CU (2x occupancy of round 9) and HALF the barrier count.
// Per chunk: stage V(c) + QK/exp(c) [wave wv -> keys wv*16..] -> barrier ->
// PV(c) [wave wv -> e-cols wv*32..] -> barrier.
// Vl rows 256 B, 16-piece XOR swizzle folded into staging SOURCE address.
// Wtb stride 132 elems (264 B rows -> b64 A-fragment reads 2-way-free).
// ---------------------------------------------------------------------------
__global__ __launch_bounds__(512, 4) void attn_kernel(
    const bf16_t* __restrict__ xk, const bf16_t* __restrict__ xq,
    const bf16_t* __restrict__ vt, const float* __restrict__ osp,
    bf16_t* __restrict__ ctx)
{
    __shared__ __align__(16) bf16_t Vl[256*128];   // 64 KB, piece-swizzled
    __shared__ __align__(16) bf16_t Wtb[32*132];   // 8.25 KB
    __shared__ float densh[8][32];
    __shared__ float dent[32];

    int tid  = threadIdx.x;
    int lane = tid & 63;
    int wv   = tid >> 6;          // 0..7
    int col  = lane & 15;
    int quad = lane >> 4;
    int l31  = lane & 31;
    int half = lane >> 5;

    // batch b pinned to XCD pair {2b,2b+1} -> its V slice L2-resident
    int bid = blockIdx.x;
    int b   = (bid & 7) >> 1;
    int qi  = ((bid >> 3) << 1) | (bid & 1);
    int q0  = qi * 32;

    float k2 = 1.4426950408889634f * osp[0];

    const bf16_t* xkb = xk + (size_t)b * SN * PAUG;
    const bf16_t* xqb = xq + (size_t)b * SN * PAUG;
    const bf16_t* vtb = vt + (size_t)b * EN * SN;

    bf16x8 qf[2][2];
    #pragma unroll
    for (int g2 = 0; g2 < 2; g2++)
        #pragma unroll
        for (int h = 0; h < 2; h++)
            qf[g2][h] = ldb8(xqb + (size_t)(q0 + g2*16 + col)*PAUG + h*32 + quad*8);

    int erow = tid >> 4;                     // 0..31
    int psw  = (tid & 15) ^ (erow & 15);     // swizzled global piece (16/row)
    const bf16_t* vsrc = vtb + (size_t)erow * SN + psw*8;

    v16f acc;
    #pragma unroll
    for (int i = 0; i < 16; i++) acc[i] = 0.f;
    float den[2] = {0.f, 0.f};
    const v4f zero = (v4f){0.f,0.f,0.f,0.f};

    for (int c = 0; c < 32; c++){
        // stage V(c): 512 thr x 8 x 16 B = 64 KB (drained by barrier below;
        // QK/exp covers latency)
        #pragma unroll
        for (int j = 0; j < 8; j++)
            glds16(vsrc + (size_t)j*32*SN + c*128, &Vl[j*4096 + tid*8]);
        // QK + exp for this wave's 16-key slice of the 128-key chunk c
        {
            const bf16_t* krow = xkb + (size_t)(c*128 + wv*16 + col)*PAUG;
            bf16x8 kf0 = ldb8(krow + quad*8);
            bf16x8 kf1 = ldb8(krow + 32 + quad*8);
            #pragma unroll
            for (int g2 = 0; g2 < 2; g2++){
                v4f st = MFMA16(kf0, qf[g2][0], zero);
                st = MFMA16(kf1, qf[g2][1], st);
                #pragma unroll
                for (int rp = 0; rp < 2; rp++){
                    float w0 = exp2f(fmaf(k2, exp2f(st[rp*2+0]), -k2));
                    float w1 = exp2f(fmaf(k2, exp2f(st[rp*2+1]), -k2));
                    den[g2] += w0 + w1;
                    *(uint32_t*)&Wtb[(g2*16+col)*132 + wv*16 + quad*4 + rp*2] = pkbf16(w0, w1);
                }
            }
        }
        __syncthreads();   // V(c) + Wtb(c) ready

        // PV chunk c: this wave's 32-e slice, 8x 32x32x16 MFMA over k=128
        bf16x8 af[8];
        #pragma unroll
        for (int subk = 0; subk < 8; subk++)
            af[subk] = ldb8u(&Wtb[l31*132 + subk*16 + half*8]);
        int sw = l31 & 15;
        const bf16_t* vrow = &Vl[(wv*32 + l31)*128];
        #pragma unroll
        for (int subk = 0; subk < 8; subk++){
            bf16x8 bf = ldb8(vrow + ((subk*2 + half) ^ sw)*8);
            acc = MFMA32(af[subk], bf, acc);
        }
        __syncthreads();   // protect Vl/Wtb before next stage
    }

    #pragma unroll
    for (int g2 = 0; g2 < 2; g2++){
        den[g2] += __shfl_xor(den[g2], 16);
        den[g2] += __shfl_xor(den[g2], 32);
    }
    if (lane < 16){
        densh[wv][lane]      = den[0];
        densh[wv][16 + lane] = den[1];
    }
    __syncthreads();
    if (tid < 32){
        float s = 0.f;
        #pragma unroll
        for (int w = 0; w < 8; w++) s += densh[w][tid];
        dent[tid] = 1.f / s;
    }
    __syncthreads();

    size_t obase = ((size_t)b*SN + q0) * EN + wv*32;
    #pragma unroll
    for (int rg = 0; rg < 16; rg++){
        int row = (rg & 3) + 8*(rg >> 2) + 4*half;
        float inv = dent[row];
        ctx[obase + (size_t)row*EN + l31] = f2b(acc[rg] * inv);
    }
}

// ---------------------------------------------------------------------------
extern "C" void kernel_launch(void* const* d_in, const int* in_sizes, int n_in,
                              void* d_out, int out_size, void* d_ws, size_t ws_size,
                              hipStream_t stream)
{
    (void)in_sizes; (void)n_in; (void)out_size; (void)ws_size;
    const float* src  = (const float*)d_in[0];
    const float* pos  = (const float*)d_in[1];
    const float* Wpos = (const float*)d_in[2];
    const float* bpos = (const float*)d_in[3];
    const float* ls   = (const float*)d_in[4];
    const float* os   = (const float*)d_in[5];
    const float* Wv   = (const float*)d_in[6];
    const float* bv   = (const float*)d_in[7];
    const float* Wo   = (const float*)d_in[8];
    const float* bo   = (const float*)d_in[9];
    const float* W1   = (const float*)d_in[10];
    const float* b1   = (const float*)d_in[11];
    const float* W2   = (const float*)d_in[12];
    const float* b2   = (const float*)d_in[13];
    const float* g1   = (const float*)d_in[14];
    const float* be1  = (const float*)d_in[15];
    const float* g2   = (const float*)d_in[16];
    const float* be2  = (const float*)d_in[17];

    char* w = (char*)d_ws;
    bf16_t* xkb  = (bf16_t*)(w);                         // 2 MB [B,S,64]
    bf16_t* xqb  = (bf16_t*)(w + ( 2u<<20));             // 2 MB
    bf16_t* Wvb  = (bf16_t*)(w + ( 4u<<20));             // 128 KB
    bf16_t* Wob  = (bf16_t*)(w + ( 4u<<20) + (1u<<18));  // 128 KB
    bf16_t* W1b  = (bf16_t*)(w + ( 5u<<20));             // 512 KB
    bf16_t* W2b  = (bf16_t*)(w + ( 6u<<20));             // 512 KB
    bf16_t* srcb = (bf16_t*)(w + ( 8u<<20));             // 8 MB (alive thru ln1)
    bf16_t* y2   = (bf16_t*)(w + ( 8u<<20));             // aliases srcb (after ln1)
    bf16_t* vtg  = (bf16_t*)(w + (16u<<20));             // 8 MB [B,E,S] (dead after attn)
    bf16_t* y1   = (bf16_t*)(w + (16u<<20));             // aliases vtg
    bf16_t* ctx  = (bf16_t*)(w + (24u<<20));             // 8 MB (dead after Wo-gemm)
    bf16_t* xws  = (bf16_t*)(w + (24u<<20));             // aliases ctx (after Wo-gemm)
    bf16_t* hws  = (bf16_t*)(w + (32u<<20));             // 32 MB

    prep_kernel<<<dim3(4800), 256, 0, stream>>>(
        src, srcb, Wv, Wvb, Wo, Wob, W1, W1b, W2, W2b,
        pos, Wpos, bpos, ls, xkb, xqb);

    // v = src @ Wv^T + bv  -> transposed store vt[b][e][s]
    gemm_t<3, bf16_t><<<dim3(BS/64, EN/64), 256, 0, stream>>>(
        srcb, Wvb, bv, (bf16_t*)nullptr, vtg, EN, EN);
    // ctx = softmax(os*exp(-0.5*d2)) @ v
    attn_kernel<<<dim3(512), 512, 0, stream>>>(xkb, xqb, vtg, os, ctx);
    // y1 = ctx @ Wo^T + bo ; x = LN1(y1 + src)
    gemm_t<0, bf16_t><<<dim3(BS/64, EN/64), 256, 0, stream>>>(
        ctx, Wob, bo, y1, (bf16_t*)nullptr, EN, EN);
    ln_kernel<bf16_t, bf16_t><<<dim3(BS/32), 256, 0, stream>>>(y1, srcb, g1, be1, xws);
    // h = relu(x @ W1^T + b1)
    gemm_t<1, bf16_t><<<dim3(BS/64, FN/64), 256, 0, stream>>>(
        xws, W1b, b1, hws, (bf16_t*)nullptr, FN, EN);
    // y2 = h @ W2^T + b2 ; out = LN2(y2 + x) -> fp32
    gemm_t<0, bf16_t><<<dim3(BS/64, EN/64), 256, 0, stream>>>(
        hws, W2b, b2, y2, (bf16_t*)nullptr, EN, FN);
    ln_kernel<float, bf16_t><<<dim3(BS/32), 256, 0, stream>>>(y2, xws, g2, be2, (float*)d_out);
}

// Round 2
// 258.224 us; speedup vs baseline: 1.1030x; 1.0766x over previous
//
#include <hip/hip_runtime.h>
#include <stdint.h>

#define BN 4
#define SN 4096
#define EN 256
#define PN 32
#define FN 1024
#define BS (BN*SN)   // 16384
#define PAUG 64      // 32 xs chans + aug (+ zero pad to 64)

typedef uint16_t bf16_t;
typedef short v4s  __attribute__((ext_vector_type(4)));
typedef short v8s  __attribute__((ext_vector_type(8)));
typedef __bf16 bf16x8 __attribute__((ext_vector_type(8)));
typedef float v4f   __attribute__((ext_vector_type(4)));
typedef float v16f  __attribute__((ext_vector_type(16)));

#define MFMA16(a,b,c) __builtin_amdgcn_mfma_f32_16x16x32_bf16(a,b,c,0,0,0)
#define MFMA32(a,b,c) __builtin_amdgcn_mfma_f32_32x32x16_bf16(a,b,c,0,0,0)

__device__ __forceinline__ float b2f(bf16_t x){
    uint32_t u = ((uint32_t)x) << 16; float f; __builtin_memcpy(&f, &u, 4); return f;
}
__device__ __forceinline__ bf16_t f2b(float f){
    uint32_t u; __builtin_memcpy(&u, &f, 4);
    u += 0x7FFFu + ((u >> 16) & 1u);           // RNE
    return (bf16_t)(u >> 16);
}
__device__ __forceinline__ bf16x8 ldb8(const bf16_t* p){
    v8s r = *(const v8s*)p; return __builtin_bit_cast(bf16x8, r);
}
// 8-B-aligned load pair (for LDS rows with odd 8-B stride -> 2-way-free banks)
__device__ __forceinline__ bf16x8 ldb8u(const bf16_t* p){
    v4s lo = *(const v4s*)p;
    v4s hi = *(const v4s*)(p + 4);
    v8s r = __builtin_shufflevector(lo, hi, 0,1,2,3,4,5,6,7);
    return __builtin_bit_cast(bf16x8, r);
}
__device__ __forceinline__ float ldsc(const float* p){ return *p; }
__device__ __forceinline__ float ldsc(const bf16_t* p){ return b2f(*p); }
__device__ __forceinline__ void stsc(float* p, float v){ *p = v; }
__device__ __forceinline__ void stsc(bf16_t* p, float v){ *p = f2b(v); }

#if __has_builtin(__builtin_amdgcn_exp2f)
__device__ __forceinline__ float fexp2(float x){ return __builtin_amdgcn_exp2f(x); }
#else
__device__ __forceinline__ float fexp2(float x){ return exp2f(x); }
#endif

#if __has_builtin(__builtin_amdgcn_cvt_pk_bf16_f32)
typedef __bf16 bf16x2 __attribute__((ext_vector_type(2)));
__device__ __forceinline__ uint32_t pkbf16(float a, float b){
    bf16x2 r = __builtin_amdgcn_cvt_pk_bf16_f32(a, b);
    return __builtin_bit_cast(uint32_t, r);
}
#else
__device__ __forceinline__ uint32_t pkbf16(float a, float b){
    return (uint32_t)f2b(a) | ((uint32_t)f2b(b) << 16);
}
#endif

typedef const __attribute__((address_space(1))) uint32_t* glds_gp;
typedef __attribute__((address_space(3))) uint32_t* glds_lp;
__device__ __forceinline__ void glds16(const bf16_t* g, bf16_t* l){
    __builtin_amdgcn_global_load_lds((glds_gp)g, (glds_lp)l, 16, 0, 0);
}

// ---------------------------------------------------------------------------
// prep: (a) src fp32->bf16, (b) 4 weight cvts, (c) posxs. One launch.
// ---------------------------------------------------------------------------
__global__ __launch_bounds__(256) void prep_kernel(
    const float* __restrict__ src, bf16_t* __restrict__ srcb,
    const float* __restrict__ Wv, bf16_t* __restrict__ Wvb,
    const float* __restrict__ Wo, bf16_t* __restrict__ Wob,
    const float* __restrict__ W1, bf16_t* __restrict__ W1b,
    const float* __restrict__ W2, bf16_t* __restrict__ W2b,
    const float* __restrict__ pos, const float* __restrict__ Wp,
    const float* __restrict__ bp,  const float* __restrict__ lsp,
    bf16_t* __restrict__ xk, bf16_t* __restrict__ xq)
{
    __shared__ float Wsh[PN*PN];
    __shared__ float bsh[PN];
    int bid = blockIdx.x;
    int tid = threadIdx.x;

    if (bid < 4736){
        const float* sp; bf16_t* dp; int off;
        if (bid < 4096){ sp = src; dp = srcb; off = (bid*256 + tid)*4; }
        else {
            int i = ((bid - 4096)*256 + tid)*4;
            if      (i <  65536){ sp=Wv; dp=Wvb; off=i; }
            else if (i < 131072){ sp=Wo; dp=Wob; off=i- 65536; }
            else if (i < 393216){ sp=W1; dp=W1b; off=i-131072; }
            else                { sp=W2; dp=W2b; off=i-393216; }
        }
        float4 f = *(const float4*)(sp + off);
        v4s o;
        o.x = (short)f2b(f.x); o.y = (short)f2b(f.y);
        o.z = (short)f2b(f.z); o.w = (short)f2b(f.w);
        *(v4s*)(dp + off) = o;
        return;
    }

    int pb = bid - 4736;          // 0..63
    int b  = pb >> 4;
    int s  = (pb & 15)*256 + tid;

    for (int i = tid; i < PN*PN; i += 256) Wsh[i] = Wp[i];
    if (tid < PN) bsh[tid] = bp[tid];
    __syncthreads();

    float inv_ls = 1.0f / lsp[0];
    const float c1f = 1.4426950408889634f;

    float col[PN];
    #pragma unroll
    for (int p = 0; p < PN; p++) col[p] = pos[((size_t)b*PN + p)*SN + s];

    uint16_t xb[PN], qb[PN];
    float sq = 0.f;
    #pragma unroll 4
    for (int o = 0; o < PN; o++){
        float pe = bsh[o];
        #pragma unroll
        for (int p = 0; p < PN; p++) pe += col[p] * Wsh[o*PN + p];
        float pv = pe * inv_ls;
        uint16_t h = f2b(pv);
        xb[o] = h;
        qb[o] = f2b(c1f * pv);
        float xr = b2f(h);
        sq += xr * xr;
    }

    size_t base = ((size_t)b*SN + s) * PAUG;
    v8s pk[8];
    #pragma unroll
    for (int c = 0; c < 4; c++)
        #pragma unroll
        for (int j = 0; j < 8; j++) ((short*)&pk[c])[j] = (short)xb[c*8 + j];
    #pragma unroll
    for (int c = 4; c < 8; c++)
        #pragma unroll
        for (int j = 0; j < 8; j++) ((short*)&pk[c])[j] = 0;
    ((short*)&pk[4])[0] = (short)f2b(-0.5f * sq);
    ((short*)&pk[4])[1] = (short)0x3F80;   // 1.0
    #pragma unroll
    for (int c = 0; c < 8; c++) *(v8s*)(xk + base + c*8) = pk[c];

    #pragma unroll
    for (int c = 0; c < 4; c++)
        #pragma unroll
        for (int j = 0; j < 8; j++) ((short*)&pk[c])[j] = (short)qb[c*8 + j];
    ((short*)&pk[4])[0] = (short)f2b(c1f);
    ((short*)&pk[4])[1] = (short)f2b(-0.5f * sq * c1f);
    #pragma unroll
    for (int c = 0; c < 8; c++) *(v8s*)(xq + base + c*8) = pk[c];
}

// ---------------------------------------------------------------------------
// gemm_t: out = A @ W^T (+bias, opt relu). Block 64m x 64n, 4 waves on m.
// BOTH A and W tiles staged via global_load_lds in 64k chunks, double-buffered
// (32 KB LDS). XOR piece-swizzle folded into the per-lane SOURCE address so
// LDS rows are 128 B and all b128 fragment reads are 2-way (free).
// EPI 0: bias ; 1: relu ; 3: bias -> store V in MFMA32 B-FRAGMENT order:
//   vfrag[b][eb(=e>>5)][k16(=s>>4)][lane(=half*32 + e&31)][r(=s&7)]
//   so the attn PV loads are coalesced b128 straight into registers.
// ---------------------------------------------------------------------------
template<int EPI, typename OutT>
__global__ __launch_bounds__(256) void gemm_t(
    const bf16_t* __restrict__ A, const bf16_t* __restrict__ W,
    const float* __restrict__ bias, OutT* __restrict__ out,
    bf16_t* __restrict__ vt, int N, int K)
{
    __shared__ __align__(16) bf16_t At[2][4096];   // 2 x 8 KB
    __shared__ __align__(16) bf16_t Wt[2][4096];   // 2 x 8 KB
    int tid = threadIdx.x;
    int lane = tid & 63, wv = tid >> 6, col = lane & 15, quad = lane >> 4;
    int m0 = blockIdx.x * 64, n0 = blockIdx.y * 64;
    int nck = K >> 6;

    int srow = tid >> 3;                      // 0..31
    int spc  = (tid & 7) ^ (srow & 7);        // swizzled source piece
    const bf16_t* asrc = A + (size_t)(m0 + srow)*K + spc*8;
    const bf16_t* wsrc = W + (size_t)(n0 + srow)*K + spc*8;

    v4f acc[4];
    #pragma unroll
    for (int t = 0; t < 4; t++) acc[t] = (v4f){0.f,0.f,0.f,0.f};

    // stage chunk 0
    glds16(asrc, &At[0][tid*8]);
    glds16(asrc + (size_t)32*K, &At[0][2048 + tid*8]);
    glds16(wsrc, &Wt[0][tid*8]);
    glds16(wsrc + (size_t)32*K, &Wt[0][2048 + tid*8]);
    __syncthreads();

    for (int c = 0; c < nck; c++){
        int cb = c & 1;
        if (c + 1 < nck){
            glds16(asrc + (c+1)*64, &At[cb^1][tid*8]);
            glds16(asrc + (size_t)32*K + (c+1)*64, &At[cb^1][2048 + tid*8]);
            glds16(wsrc + (c+1)*64, &Wt[cb^1][tid*8]);
            glds16(wsrc + (size_t)32*K + (c+1)*64, &Wt[cb^1][2048 + tid*8]);
        }
        #pragma unroll
        for (int kc = 0; kc < 2; kc++){
            int pc = ((kc*4 + quad) ^ (col & 7)) * 8;
            bf16x8 a = ldb8(&At[cb][(wv*16 + col)*64 + pc]);
            #pragma unroll
            for (int t = 0; t < 4; t++){
                bf16x8 b = ldb8(&Wt[cb][(t*16 + col)*64 + pc]);
                acc[t] = MFMA16(a, b, acc[t]);
            }
        }
        __syncthreads();
    }

    float bfv[4];
    #pragma unroll
    for (int t = 0; t < 4; t++) bfv[t] = bias[n0 + t*16 + col];

    if constexpr (EPI == 3){
        __shared__ uint16_t Tsh[64*74];
        #pragma unroll
        for (int r = 0; r < 4; r++)
            #pragma unroll
            for (int t = 0; t < 4; t++)
                Tsh[(wv*16 + quad*4 + r)*74 + t*16 + col] = f2b(acc[t][r] + bfv[t]);
        __syncthreads();
        int e = tid >> 2, sc = tid & 3;
        int b = m0 >> 12;
        int sbat = m0 & (SN-1);
        int eb   = (n0 + e) >> 5;
        int l31e = (n0 + e) & 31;
        int k16  = (sbat >> 4) + sc;
        v8s p0, p1;
        #pragma unroll
        for (int i = 0; i < 8; i++) ((short*)&p0)[i] = (short)Tsh[(sc*16 + i)*74 + e];
        #pragma unroll
        for (int i = 0; i < 8; i++) ((short*)&p1)[i] = (short)Tsh[(sc*16 + 8 + i)*74 + e];
        bf16_t* dst = vt + ((((size_t)b*8 + eb)*256 + k16)*64 + l31e)*8;
        *(v8s*)dst = p0;              // half 0 (keys s&15 in 0..7)
        *(v8s*)(dst + 256) = p1;      // half 1 (keys s&15 in 8..15), +32 lanes
    } else {
        #pragma unroll
        for (int r = 0; r < 4; r++){
            int row = m0 + wv*16 + quad*4 + r;
            #pragma unroll
            for (int t = 0; t < 4; t++){
                float y = acc[t][r] + bfv[t];
                if constexpr (EPI == 1) y = fmaxf(y, 0.f);
                stsc(out + (size_t)row*N + n0 + t*16 + col, y);
            }
        }
    }
}

// ---------------------------------------------------------------------------
// ln_kernel: out = LayerNorm(y + res) * gamma + beta.  32 rows/block.
// ---------------------------------------------------------------------------
template<typename OutT, typename ResT>
__global__ __launch_bounds__(256) void ln_kernel(
    const bf16_t* __restrict__ y, const ResT* __restrict__ res,
    const float* __restrict__ gamma, const float* __restrict__ beta,
    OutT* __restrict__ out)
{
    int tid = threadIdx.x;
    int row = blockIdx.x * 32 + (tid >> 3);
    int l8  = tid & 7;
    size_t base = (size_t)row * EN;
    float v[32];
    float s1 = 0.f, s2 = 0.f;
    #pragma unroll
    for (int i = 0; i < 4; i++){
        int off = l8*8 + i*64;
        v8s a = *(const v8s*)(y + base + off);
        #pragma unroll
        for (int j = 0; j < 8; j++){
            float t = b2f((bf16_t)(uint16_t)a[j]) + ldsc(res + base + off + j);
            v[i*8 + j] = t; s1 += t; s2 += t*t;
        }
    }
    #pragma unroll
    for (int m = 1; m <= 4; m <<= 1){
        s1 += __shfl_xor(s1, m);
        s2 += __shfl_xor(s2, m);
    }
    float mu = s1 * (1.f/256.f);
    float rs = rsqrtf(s2 * (1.f/256.f) - mu*mu + 1e-5f);
    #pragma unroll
    for (int i = 0; i < 4; i++){
        int off = l8*8 + i*64;
        #pragma unroll
        for (int j = 0; j < 8; j++)
            stsc(out + base + off + j, (v[i*8+j]-mu)*rs*gamma[off+j] + beta[off+j]);
    }
}

// ---------------------------------------------------------------------------
// Attention round 11: V pre-fragmented in global (vfrag) -> PV B-operands are
// coalesced b128 GLOBAL loads straight into registers. NO V LDS staging, no
// vmcnt staging drain. Wtb double-buffered -> ONE barrier per chunk.
// Per chunk: issue vr(c) -> QK/exp(c) w/ prefetched kf -> barrier ->
// issue kf(c+1) -> PV(c) (af from Wtb[c&1], vr regs).
// Race-safe: QK(c+1) writes Wtb[(c+1)&1]; reuse of parity c&1 requires
// passing barrier(c+1), which every wave reaches only after PV(c).
// ---------------------------------------------------------------------------
__global__ __launch_bounds__(512, 4) void attn_kernel(
    const bf16_t* __restrict__ xk, const bf16_t* __restrict__ xq,
    const bf16_t* __restrict__ vf, const float* __restrict__ osp,
    bf16_t* __restrict__ ctx)
{
    __shared__ __align__(16) bf16_t Wtb[2][32*132];   // 16.5 KB
    __shared__ float densh[8][32];
    __shared__ float dent[32];

    int tid  = threadIdx.x;
    int lane = tid & 63;
    int wv   = tid >> 6;          // 0..7
    int col  = lane & 15;
    int quad = lane >> 4;
    int l31  = lane & 31;
    int half = lane >> 5;

    // batch b pinned to XCD pair {2b,2b+1} -> its V slice L2-resident
    int bid = blockIdx.x;
    int b   = (bid & 7) >> 1;
    int qi  = ((bid >> 3) << 1) | (bid & 1);
    int q0  = qi * 32;

    float k2 = 1.4426950408889634f * osp[0];

    const bf16_t* xkb = xk + (size_t)b * SN * PAUG;
    const bf16_t* xqb = xq + (size_t)b * SN * PAUG;
    // this wave's V-fragment stream: [k16 = 0..255][lane][8]
    const bf16_t* vfb = vf + (((size_t)b*8 + wv)*256)*512 + lane*8;

    bf16x8 qf[2][2];
    #pragma unroll
    for (int g2 = 0; g2 < 2; g2++)
        #pragma unroll
        for (int h = 0; h < 2; h++)
            qf[g2][h] = ldb8(xqb + (size_t)(q0 + g2*16 + col)*PAUG + h*32 + quad*8);

    v16f acc;
    #pragma unroll
    for (int i = 0; i < 16; i++) acc[i] = 0.f;
    float den[2] = {0.f, 0.f};
    const v4f zero = (v4f){0.f,0.f,0.f,0.f};

    // prologue: kf(0)
    const bf16_t* krow0 = xkb + (size_t)(wv*16 + col)*PAUG + quad*8;
    bf16x8 kf0 = ldb8(krow0);
    bf16x8 kf1 = ldb8(krow0 + 32);

    for (int c = 0; c < 32; c++){
        int cb = c & 1;
        // issue V(c) fragment loads (8 coalesced b128; QK covers L2 latency)
        bf16x8 vr[8];
        #pragma unroll
        for (int subk = 0; subk < 8; subk++)
            vr[subk] = ldb8(vfb + (size_t)(c*8 + subk)*512);

        // QK + exp for this wave's 16-key slice of the 128-key chunk c
        #pragma unroll
        for (int g2 = 0; g2 < 2; g2++){
            v4f st = MFMA16(kf0, qf[g2][0], zero);
            st = MFMA16(kf1, qf[g2][1], st);
            #pragma unroll
            for (int rp = 0; rp < 2; rp++){
                float w0 = fexp2(fmaf(k2, fexp2(st[rp*2+0]), -k2));
                float w1 = fexp2(fmaf(k2, fexp2(st[rp*2+1]), -k2));
                den[g2] += w0 + w1;
                *(uint32_t*)&Wtb[cb][(g2*16+col)*132 + wv*16 + quad*4 + rp*2] = pkbf16(w0, w1);
            }
        }
        __syncthreads();   // Wtb[cb] ready; drains vr(c) (needed now anyway)

        // prefetch kf(c+1) (covered by PV below)
        if (c + 1 < 32){
            const bf16_t* krow = xkb + (size_t)((c+1)*128 + wv*16 + col)*PAUG + quad*8;
            kf0 = ldb8(krow);
            kf1 = ldb8(krow + 32);
        }

        // PV chunk c: this wave's 32-e slice, 8x 32x32x16 MFMA over k=128
        #pragma unroll
        for (int sk4 = 0; sk4 < 2; sk4++){
            bf16x8 af[4];
            #pragma unroll
            for (int j = 0; j < 4; j++)
                af[j] = ldb8u(&Wtb[cb][l31*132 + (sk4*4 + j)*16 + half*8]);
            #pragma unroll
            for (int j = 0; j < 4; j++)
                acc = MFMA32(af[j], vr[sk4*4 + j], acc);
        }
    }

    #pragma unroll
    for (int g2 = 0; g2 < 2; g2++){
        den[g2] += __shfl_xor(den[g2], 16);
        den[g2] += __shfl_xor(den[g2], 32);
    }
    if (lane < 16){
        densh[wv][lane]      = den[0];
        densh[wv][16 + lane] = den[1];
    }
    __syncthreads();
    if (tid < 32){
        float s = 0.f;
        #pragma unroll
        for (int w = 0; w < 8; w++) s += densh[w][tid];
        dent[tid] = 1.f / s;
    }
    __syncthreads();

    size_t obase = ((size_t)b*SN + q0) * EN + wv*32;
    #pragma unroll
    for (int rg = 0; rg < 16; rg++){
        int row = (rg & 3) + 8*(rg >> 2) + 4*half;
        float inv = dent[row];
        ctx[obase + (size_t)row*EN + l31] = f2b(acc[rg] * inv);
    }
}

// ---------------------------------------------------------------------------
extern "C" void kernel_launch(void* const* d_in, const int* in_sizes, int n_in,
                              void* d_out, int out_size, void* d_ws, size_t ws_size,
                              hipStream_t stream)
{
    (void)in_sizes; (void)n_in; (void)out_size; (void)ws_size;
    const float* src  = (const float*)d_in[0];
    const float* pos  = (const float*)d_in[1];
    const float* Wpos = (const float*)d_in[2];
    const float* bpos = (const float*)d_in[3];
    const float* ls   = (const float*)d_in[4];
    const float* os   = (const float*)d_in[5];
    const float* Wv   = (const float*)d_in[6];
    const float* bv   = (const float*)d_in[7];
    const float* Wo   = (const float*)d_in[8];
    const float* bo   = (const float*)d_in[9];
    const float* W1   = (const float*)d_in[10];
    const float* b1   = (const float*)d_in[11];
    const float* W2   = (const float*)d_in[12];
    const float* b2   = (const float*)d_in[13];
    const float* g1   = (const float*)d_in[14];
    const float* be1  = (const float*)d_in[15];
    const float* g2   = (const float*)d_in[16];
    const float* be2  = (const float*)d_in[17];

    char* w = (char*)d_ws;
    bf16_t* xkb  = (bf16_t*)(w);                         // 2 MB [B,S,64]
    bf16_t* xqb  = (bf16_t*)(w + ( 2u<<20));             // 2 MB
    bf16_t* Wvb  = (bf16_t*)(w + ( 4u<<20));             // 128 KB
    bf16_t* Wob  = (bf16_t*)(w + ( 4u<<20) + (1u<<18));  // 128 KB
    bf16_t* W1b  = (bf16_t*)(w + ( 5u<<20));             // 512 KB
    bf16_t* W2b  = (bf16_t*)(w + ( 6u<<20));             // 512 KB
    bf16_t* srcb = (bf16_t*)(w + ( 8u<<20));             // 8 MB (alive thru ln1)
    bf16_t* y2   = (bf16_t*)(w + ( 8u<<20));             // aliases srcb (after ln1)
    bf16_t* vtg  = (bf16_t*)(w + (16u<<20));             // 8 MB vfrag (dead after attn)
    bf16_t* y1   = (bf16_t*)(w + (16u<<20));             // aliases vtg
    bf16_t* ctx  = (bf16_t*)(w + (24u<<20));             // 8 MB (dead after Wo-gemm)
    bf16_t* xws  = (bf16_t*)(w + (24u<<20));             // aliases ctx (after Wo-gemm)
    bf16_t* hws  = (bf16_t*)(w + (32u<<20));             // 32 MB

    prep_kernel<<<dim3(4800), 256, 0, stream>>>(
        src, srcb, Wv, Wvb, Wo, Wob, W1, W1b, W2, W2b,
        pos, Wpos, bpos, ls, xkb, xqb);

    // v = src @ Wv^T + bv  -> fragment-ordered store vfrag[b][eb][k16][lane][8]
    gemm_t<3, bf16_t><<<dim3(BS/64, EN/64), 256, 0, stream>>>(
        srcb, Wvb, bv, (bf16_t*)nullptr, vtg, EN, EN);
    // ctx = softmax(os*exp(-0.5*d2)) @ v
    attn_kernel<<<dim3(512), 512, 0, stream>>>(xkb, xqb, vtg, os, ctx);
    // y1 = ctx @ Wo^T + bo ; x = LN1(y1 + src)
    gemm_t<0, bf16_t><<<dim3(BS/64, EN/64), 256, 0, stream>>>(
        ctx, Wob, bo, y1, (bf16_t*)nullptr, EN, EN);
    ln_kernel<bf16_t, bf16_t><<<dim3(BS/32), 256, 0, stream>>>(y1, srcb, g1, be1, xws);
    // h = relu(x @ W1^T + b1)
    gemm_t<1, bf16_t><<<dim3(BS/64, FN/64), 256, 0, stream>>>(
        xws, W1b, b1, hws, (bf16_t*)nullptr, FN, EN);
    // y2 = h @ W2^T + b2 ; out = LN2(y2 + x) -> fp32
    gemm_t<0, bf16_t><<<dim3(BS/64, EN/64), 256, 0, stream>>>(
        hws, W2b, b2, y2, (bf16_t*)nullptr, EN, FN);
    ln_kernel<float, bf16_t><<<dim3(BS/32), 256, 0, stream>>>(y2, xws, g2, be2, (float*)d_out);
}

// Round 3
// 243.008 us; speedup vs baseline: 1.1721x; 1.0626x over previous
//
#include <hip/hip_runtime.h>
#include <stdint.h>

#define BN 4
#define SN 4096
#define EN 256
#define PN 32
#define FN 1024
#define BS (BN*SN)   // 16384
#define PAUG 64      // 32 xs chans + aug (+ zero pad to 64)

typedef uint16_t bf16_t;
typedef short v4s  __attribute__((ext_vector_type(4)));
typedef short v8s  __attribute__((ext_vector_type(8)));
typedef __bf16 bf16x8 __attribute__((ext_vector_type(8)));
typedef float v4f   __attribute__((ext_vector_type(4)));
typedef float v16f  __attribute__((ext_vector_type(16)));

#define MFMA16(a,b,c) __builtin_amdgcn_mfma_f32_16x16x32_bf16(a,b,c,0,0,0)
#define MFMA32(a,b,c) __builtin_amdgcn_mfma_f32_32x32x16_bf16(a,b,c,0,0,0)

__device__ __forceinline__ float b2f(bf16_t x){
    uint32_t u = ((uint32_t)x) << 16; float f; __builtin_memcpy(&f, &u, 4); return f;
}
__device__ __forceinline__ bf16_t f2b(float f){
    uint32_t u; __builtin_memcpy(&u, &f, 4);
    u += 0x7FFFu + ((u >> 16) & 1u);           // RNE
    return (bf16_t)(u >> 16);
}
__device__ __forceinline__ bf16x8 ldb8(const bf16_t* p){
    v8s r = *(const v8s*)p; return __builtin_bit_cast(bf16x8, r);
}
// 8-B-aligned load pair (for LDS rows with odd 8-B stride -> 2-way-free banks)
__device__ __forceinline__ bf16x8 ldb8u(const bf16_t* p){
    v4s lo = *(const v4s*)p;
    v4s hi = *(const v4s*)(p + 4);
    v8s r = __builtin_shufflevector(lo, hi, 0,1,2,3,4,5,6,7);
    return __builtin_bit_cast(bf16x8, r);
}
__device__ __forceinline__ float ldsc(const float* p){ return *p; }
__device__ __forceinline__ float ldsc(const bf16_t* p){ return b2f(*p); }
__device__ __forceinline__ void stsc(float* p, float v){ *p = v; }
__device__ __forceinline__ void stsc(bf16_t* p, float v){ *p = f2b(v); }

#if __has_builtin(__builtin_amdgcn_exp2f)
__device__ __forceinline__ float fexp2(float x){ return __builtin_amdgcn_exp2f(x); }
#else
__device__ __forceinline__ float fexp2(float x){ return exp2f(x); }
#endif

#if __has_builtin(__builtin_amdgcn_cvt_pk_bf16_f32)
typedef __bf16 bf16x2 __attribute__((ext_vector_type(2)));
__device__ __forceinline__ uint32_t pkbf16(float a, float b){
    bf16x2 r = __builtin_amdgcn_cvt_pk_bf16_f32(a, b);
    return __builtin_bit_cast(uint32_t, r);
}
#else
__device__ __forceinline__ uint32_t pkbf16(float a, float b){
    return (uint32_t)f2b(a) | ((uint32_t)f2b(b) << 16);
}
#endif

typedef const __attribute__((address_space(1))) uint32_t* glds_gp;
typedef __attribute__((address_space(3))) uint32_t* glds_lp;
__device__ __forceinline__ void glds16(const bf16_t* g, bf16_t* l){
    __builtin_amdgcn_global_load_lds((glds_gp)g, (glds_lp)l, 16, 0, 0);
}

// ---------------------------------------------------------------------------
// prep: (a) src fp32->bf16, (b) 4 weight cvts, (c) posxs. One launch.
// ---------------------------------------------------------------------------
__global__ __launch_bounds__(256) void prep_kernel(
    const float* __restrict__ src, bf16_t* __restrict__ srcb,
    const float* __restrict__ Wv, bf16_t* __restrict__ Wvb,
    const float* __restrict__ Wo, bf16_t* __restrict__ Wob,
    const float* __restrict__ W1, bf16_t* __restrict__ W1b,
    const float* __restrict__ W2, bf16_t* __restrict__ W2b,
    const float* __restrict__ pos, const float* __restrict__ Wp,
    const float* __restrict__ bp,  const float* __restrict__ lsp,
    bf16_t* __restrict__ xk, bf16_t* __restrict__ xq)
{
    __shared__ float Wsh[PN*PN];
    __shared__ float bsh[PN];
    int bid = blockIdx.x;
    int tid = threadIdx.x;

    if (bid < 4736){
        const float* sp; bf16_t* dp; int off;
        if (bid < 4096){ sp = src; dp = srcb; off = (bid*256 + tid)*4; }
        else {
            int i = ((bid - 4096)*256 + tid)*4;
            if      (i <  65536){ sp=Wv; dp=Wvb; off=i; }
            else if (i < 131072){ sp=Wo; dp=Wob; off=i- 65536; }
            else if (i < 393216){ sp=W1; dp=W1b; off=i-131072; }
            else                { sp=W2; dp=W2b; off=i-393216; }
        }
        float4 f = *(const float4*)(sp + off);
        v4s o;
        o.x = (short)f2b(f.x); o.y = (short)f2b(f.y);
        o.z = (short)f2b(f.z); o.w = (short)f2b(f.w);
        *(v4s*)(dp + off) = o;
        return;
    }

    int pb = bid - 4736;          // 0..63
    int b  = pb >> 4;
    int s  = (pb & 15)*256 + tid;

    for (int i = tid; i < PN*PN; i += 256) Wsh[i] = Wp[i];
    if (tid < PN) bsh[tid] = bp[tid];
    __syncthreads();

    float inv_ls = 1.0f / lsp[0];
    const float c1f = 1.4426950408889634f;

    float col[PN];
    #pragma unroll
    for (int p = 0; p < PN; p++) col[p] = pos[((size_t)b*PN + p)*SN + s];

    uint16_t xb[PN], qb[PN];
    float sq = 0.f;
    #pragma unroll 4
    for (int o = 0; o < PN; o++){
        float pe = bsh[o];
        #pragma unroll
        for (int p = 0; p < PN; p++) pe += col[p] * Wsh[o*PN + p];
        float pv = pe * inv_ls;
        uint16_t h = f2b(pv);
        xb[o] = h;
        qb[o] = f2b(c1f * pv);
        float xr = b2f(h);
        sq += xr * xr;
    }

    size_t base = ((size_t)b*SN + s) * PAUG;
    v8s pk[8];
    #pragma unroll
    for (int c = 0; c < 4; c++)
        #pragma unroll
        for (int j = 0; j < 8; j++) ((short*)&pk[c])[j] = (short)xb[c*8 + j];
    #pragma unroll
    for (int c = 4; c < 8; c++)
        #pragma unroll
        for (int j = 0; j < 8; j++) ((short*)&pk[c])[j] = 0;
    ((short*)&pk[4])[0] = (short)f2b(-0.5f * sq);
    ((short*)&pk[4])[1] = (short)0x3F80;   // 1.0
    #pragma unroll
    for (int c = 0; c < 8; c++) *(v8s*)(xk + base + c*8) = pk[c];

    #pragma unroll
    for (int c = 0; c < 4; c++)
        #pragma unroll
        for (int j = 0; j < 8; j++) ((short*)&pk[c])[j] = (short)qb[c*8 + j];
    ((short*)&pk[4])[0] = (short)f2b(c1f);
    ((short*)&pk[4])[1] = (short)f2b(-0.5f * sq * c1f);
    #pragma unroll
    for (int c = 0; c < 8; c++) *(v8s*)(xq + base + c*8) = pk[c];
}

// ---------------------------------------------------------------------------
// gemm_t: out = A @ W^T (+bias, opt relu). Block 64m x 64n, 4 waves on m.
// BOTH A and W tiles staged via global_load_lds in 64k chunks, double-buffered
// (32 KB LDS). XOR piece-swizzle folded into the per-lane SOURCE address so
// LDS rows are 128 B and all b128 fragment reads are 2-way (free).
// EPI 0: bias ; 1: relu ; 3: bias -> store V in MFMA32 B-FRAGMENT order:
//   vfrag[b][eb(=e>>5)][k16(=s>>4)][lane(=half*32 + e&31)][r(=s&7)]
//   so the attn PV loads are coalesced b128 straight into registers.
// ---------------------------------------------------------------------------
template<int EPI, typename OutT>
__global__ __launch_bounds__(256) void gemm_t(
    const bf16_t* __restrict__ A, const bf16_t* __restrict__ W,
    const float* __restrict__ bias, OutT* __restrict__ out,
    bf16_t* __restrict__ vt, int N, int K)
{
    __shared__ __align__(16) bf16_t At[2][4096];   // 2 x 8 KB
    __shared__ __align__(16) bf16_t Wt[2][4096];   // 2 x 8 KB
    int tid = threadIdx.x;
    int lane = tid & 63, wv = tid >> 6, col = lane & 15, quad = lane >> 4;
    int m0 = blockIdx.x * 64, n0 = blockIdx.y * 64;
    int nck = K >> 6;

    int srow = tid >> 3;                      // 0..31
    int spc  = (tid & 7) ^ (srow & 7);        // swizzled source piece
    const bf16_t* asrc = A + (size_t)(m0 + srow)*K + spc*8;
    const bf16_t* wsrc = W + (size_t)(n0 + srow)*K + spc*8;

    v4f acc[4];
    #pragma unroll
    for (int t = 0; t < 4; t++) acc[t] = (v4f){0.f,0.f,0.f,0.f};

    // stage chunk 0
    glds16(asrc, &At[0][tid*8]);
    glds16(asrc + (size_t)32*K, &At[0][2048 + tid*8]);
    glds16(wsrc, &Wt[0][tid*8]);
    glds16(wsrc + (size_t)32*K, &Wt[0][2048 + tid*8]);
    __syncthreads();

    for (int c = 0; c < nck; c++){
        int cb = c & 1;
        if (c + 1 < nck){
            glds16(asrc + (c+1)*64, &At[cb^1][tid*8]);
            glds16(asrc + (size_t)32*K + (c+1)*64, &At[cb^1][2048 + tid*8]);
            glds16(wsrc + (c+1)*64, &Wt[cb^1][tid*8]);
            glds16(wsrc + (size_t)32*K + (c+1)*64, &Wt[cb^1][2048 + tid*8]);
        }
        #pragma unroll
        for (int kc = 0; kc < 2; kc++){
            int pc = ((kc*4 + quad) ^ (col & 7)) * 8;
            bf16x8 a = ldb8(&At[cb][(wv*16 + col)*64 + pc]);
            #pragma unroll
            for (int t = 0; t < 4; t++){
                bf16x8 b = ldb8(&Wt[cb][(t*16 + col)*64 + pc]);
                acc[t] = MFMA16(a, b, acc[t]);
            }
        }
        __syncthreads();
    }

    float bfv[4];
    #pragma unroll
    for (int t = 0; t < 4; t++) bfv[t] = bias[n0 + t*16 + col];

    if constexpr (EPI == 3){
        __shared__ uint16_t Tsh[64*74];
        #pragma unroll
        for (int r = 0; r < 4; r++)
            #pragma unroll
            for (int t = 0; t < 4; t++)
                Tsh[(wv*16 + quad*4 + r)*74 + t*16 + col] = f2b(acc[t][r] + bfv[t]);
        __syncthreads();
        int e = tid >> 2, sc = tid & 3;
        int b = m0 >> 12;
        int sbat = m0 & (SN-1);
        int eb   = (n0 + e) >> 5;
        int l31e = (n0 + e) & 31;
        int k16  = (sbat >> 4) + sc;
        v8s p0, p1;
        #pragma unroll
        for (int i = 0; i < 8; i++) ((short*)&p0)[i] = (short)Tsh[(sc*16 + i)*74 + e];
        #pragma unroll
        for (int i = 0; i < 8; i++) ((short*)&p1)[i] = (short)Tsh[(sc*16 + 8 + i)*74 + e];
        bf16_t* dst = vt + ((((size_t)b*8 + eb)*256 + k16)*64 + l31e)*8;
        *(v8s*)dst = p0;              // half 0 (keys s&15 in 0..7)
        *(v8s*)(dst + 256) = p1;      // half 1 (keys s&15 in 8..15), +32 lanes
    } else {
        #pragma unroll
        for (int r = 0; r < 4; r++){
            int row = m0 + wv*16 + quad*4 + r;
            #pragma unroll
            for (int t = 0; t < 4; t++){
                float y = acc[t][r] + bfv[t];
                if constexpr (EPI == 1) y = fmaxf(y, 0.f);
                stsc(out + (size_t)row*N + n0 + t*16 + col, y);
            }
        }
    }
}

// ---------------------------------------------------------------------------
// ln_kernel: out = LayerNorm(y + res) * gamma + beta.  32 rows/block.
// ---------------------------------------------------------------------------
template<typename OutT, typename ResT>
__global__ __launch_bounds__(256) void ln_kernel(
    const bf16_t* __restrict__ y, const ResT* __restrict__ res,
    const float* __restrict__ gamma, const float* __restrict__ beta,
    OutT* __restrict__ out)
{
    int tid = threadIdx.x;
    int row = blockIdx.x * 32 + (tid >> 3);
    int l8  = tid & 7;
    size_t base = (size_t)row * EN;
    float v[32];
    float s1 = 0.f, s2 = 0.f;
    #pragma unroll
    for (int i = 0; i < 4; i++){
        int off = l8*8 + i*64;
        v8s a = *(const v8s*)(y + base + off);
        #pragma unroll
        for (int j = 0; j < 8; j++){
            float t = b2f((bf16_t)(uint16_t)a[j]) + ldsc(res + base + off + j);
            v[i*8 + j] = t; s1 += t; s2 += t*t;
        }
    }
    #pragma unroll
    for (int m = 1; m <= 4; m <<= 1){
        s1 += __shfl_xor(s1, m);
        s2 += __shfl_xor(s2, m);
    }
    float mu = s1 * (1.f/256.f);
    float rs = rsqrtf(s2 * (1.f/256.f) - mu*mu + 1e-5f);
    #pragma unroll
    for (int i = 0; i < 4; i++){
        int off = l8*8 + i*64;
        #pragma unroll
        for (int j = 0; j < 8; j++)
            stsc(out + base + off + j, (v[i*8+j]-mu)*rs*gamma[off+j] + beta[off+j]);
    }
}

// ---------------------------------------------------------------------------
// Attention round 12: Q=64/block, grid 256 (1 block/CU), chunk=256 keys,
// 16 chunks -> L2 traffic halved vs round 11 (each block reads V slice once
// for 64 q rows). V stays pre-fragmented in global (vfrag) -> PV B-operands
// coalesced b128 loads straight into registers (16 outstanding/wave/chunk).
// Q tile (64x64) staged ONCE into LDS (piece-swizzled source, linear dest),
// read back as MFMA16 B-fragments at 2-way-free banks -> saves 64 VGPRs.
// Wtb[2][64*260] double-buffered, ONE barrier per chunk (write parity c&1,
// read after barrier; next write goes to parity (c+1)&1 -> race-free).
// ---------------------------------------------------------------------------
__global__ __launch_bounds__(512, 2) void attn_kernel(
    const bf16_t* __restrict__ xk, const bf16_t* __restrict__ xq,
    const bf16_t* __restrict__ vf, const float* __restrict__ osp,
    bf16_t* __restrict__ ctx)
{
    __shared__ __align__(16) bf16_t Wtb[2][64*260];   // 65 KB
    __shared__ __align__(16) bf16_t Qs[64*64];        // 8 KB
    __shared__ float densh[8][64];
    __shared__ float dent[64];

    int tid  = threadIdx.x;
    int lane = tid & 63;
    int wv   = tid >> 6;          // 0..7
    int col  = lane & 15;
    int quad = lane >> 4;
    int l31  = lane & 31;
    int half = lane >> 5;

    // batch b pinned to XCD pair {2b,2b+1} -> its V slice L2-resident
    int bid = blockIdx.x;                    // 0..255
    int b   = (bid & 7) >> 1;
    int qi  = ((bid >> 3) << 1) | (bid & 1); // 0..63
    int q0  = qi * 64;

    float k2 = 1.4426950408889634f * osp[0];

    const bf16_t* xkb = xk + (size_t)b * SN * PAUG;
    const bf16_t* xqb = xq + (size_t)b * SN * PAUG;
    // this wave's V-fragment stream: [k16 = 0..255][lane][8]
    const bf16_t* vfb = vf + (((size_t)b*8 + wv)*256)*512 + lane*8;

    // stage Q tile: 512 thr x 16 B = 8 KB, piece-swizzled SOURCE, linear dest
    {
        int qrow = tid >> 3;                 // 0..63
        int qpc  = (tid & 7) ^ (qrow & 7);
        glds16(xqb + (size_t)(q0 + qrow)*PAUG + qpc*8, &Qs[tid*8]);
    }

    v16f acc[2];
    #pragma unroll
    for (int qg = 0; qg < 2; qg++)
        #pragma unroll
        for (int i = 0; i < 16; i++) acc[qg][i] = 0.f;
    float den[4] = {0.f, 0.f, 0.f, 0.f};     // [qg*2+g2]
    const v4f zero = (v4f){0.f,0.f,0.f,0.f};

    // kf prologue (chunk 0): this wave's 32 keys, 2 k-groups x 2 paug-halves
    bf16x8 kf[2][2];
    #pragma unroll
    for (int kg = 0; kg < 2; kg++)
        #pragma unroll
        for (int h = 0; h < 2; h++)
            kf[kg][h] = ldb8(xkb + (size_t)(wv*32 + kg*16 + col)*PAUG + h*32 + quad*8);

    __syncthreads();   // Qs staged

    for (int c = 0; c < 16; c++){
        int cb = c & 1;
        // issue V(c): 16 coalesced b128 into regs (QK covers L2 latency)
        bf16x8 vr[16];
        #pragma unroll
        for (int sk = 0; sk < 16; sk++)
            vr[sk] = ldb8(vfb + (size_t)(c*16 + sk)*512);

        // QK + exp: this wave's 32-key slice x 64 q of chunk c
        #pragma unroll
        for (int qg = 0; qg < 2; qg++){
            #pragma unroll
            for (int g2 = 0; g2 < 2; g2++){
                int qr = qg*32 + g2*16 + col;
                bf16x8 qa = ldb8(&Qs[qr*64 + ((quad    ) ^ (col & 7))*8]);
                bf16x8 qb = ldb8(&Qs[qr*64 + ((4 + quad) ^ (col & 7))*8]);
                #pragma unroll
                for (int kg = 0; kg < 2; kg++){
                    v4f st = MFMA16(kf[kg][0], qa, zero);
                    st = MFMA16(kf[kg][1], qb, st);
                    #pragma unroll
                    for (int rp = 0; rp < 2; rp++){
                        float w0 = fexp2(fmaf(k2, fexp2(st[rp*2+0]), -k2));
                        float w1 = fexp2(fmaf(k2, fexp2(st[rp*2+1]), -k2));
                        den[qg*2+g2] += w0 + w1;
                        *(uint32_t*)&Wtb[cb][qr*260 + wv*32 + kg*16 + quad*4 + rp*2]
                            = pkbf16(w0, w1);
                    }
                }
            }
        }
        __syncthreads();   // Wtb[cb] ready; vr(c) drains (needed now anyway)

        // prefetch kf(c+1) (covered by PV below)
        if (c + 1 < 16){
            #pragma unroll
            for (int kg = 0; kg < 2; kg++)
                #pragma unroll
                for (int h = 0; h < 2; h++)
                    kf[kg][h] = ldb8(xkb + (size_t)((c+1)*256 + wv*32 + kg*16 + col)*PAUG
                                     + h*32 + quad*8);
        }

        // PV chunk c: this wave's 32-e slice, 2 qg x 16 MFMA32 over k=256
        #pragma unroll
        for (int qg = 0; qg < 2; qg++){
            #pragma unroll
            for (int sk4 = 0; sk4 < 4; sk4++){
                bf16x8 af[4];
                #pragma unroll
                for (int j = 0; j < 4; j++)
                    af[j] = ldb8u(&Wtb[cb][(qg*32 + l31)*260 + (sk4*4 + j)*16 + half*8]);
                #pragma unroll
                for (int j = 0; j < 4; j++)
                    acc[qg] = MFMA32(af[j], vr[sk4*4 + j], acc[qg]);
            }
        }
    }

    #pragma unroll
    for (int d = 0; d < 4; d++){
        den[d] += __shfl_xor(den[d], 16);
        den[d] += __shfl_xor(den[d], 32);
    }
    if (lane < 16){
        #pragma unroll
        for (int qg = 0; qg < 2; qg++)
            #pragma unroll
            for (int g2 = 0; g2 < 2; g2++)
                densh[wv][qg*32 + g2*16 + lane] = den[qg*2+g2];
    }
    __syncthreads();
    if (tid < 64){
        float s = 0.f;
        #pragma unroll
        for (int w = 0; w < 8; w++) s += densh[w][tid];
        dent[tid] = 1.f / s;
    }
    __syncthreads();

    size_t obase = ((size_t)b*SN + q0) * EN + wv*32;
    #pragma unroll
    for (int qg = 0; qg < 2; qg++){
        #pragma unroll
        for (int rg = 0; rg < 16; rg++){
            int row = (rg & 3) + 8*(rg >> 2) + 4*half;
            float inv = dent[qg*32 + row];
            ctx[obase + (size_t)(qg*32 + row)*EN + l31] = f2b(acc[qg][rg] * inv);
        }
    }
}

// ---------------------------------------------------------------------------
extern "C" void kernel_launch(void* const* d_in, const int* in_sizes, int n_in,
                              void* d_out, int out_size, void* d_ws, size_t ws_size,
                              hipStream_t stream)
{
    (void)in_sizes; (void)n_in; (void)out_size; (void)ws_size;
    const float* src  = (const float*)d_in[0];
    const float* pos  = (const float*)d_in[1];
    const float* Wpos = (const float*)d_in[2];
    const float* bpos = (const float*)d_in[3];
    const float* ls   = (const float*)d_in[4];
    const float* os   = (const float*)d_in[5];
    const float* Wv   = (const float*)d_in[6];
    const float* bv   = (const float*)d_in[7];
    const float* Wo   = (const float*)d_in[8];
    const float* bo   = (const float*)d_in[9];
    const float* W1   = (const float*)d_in[10];
    const float* b1   = (const float*)d_in[11];
    const float* W2   = (const float*)d_in[12];
    const float* b2   = (const float*)d_in[13];
    const float* g1   = (const float*)d_in[14];
    const float* be1  = (const float*)d_in[15];
    const float* g2   = (const float*)d_in[16];
    const float* be2  = (const float*)d_in[17];

    char* w = (char*)d_ws;
    bf16_t* xkb  = (bf16_t*)(w);                         // 2 MB [B,S,64]
    bf16_t* xqb  = (bf16_t*)(w + ( 2u<<20));             // 2 MB
    bf16_t* Wvb  = (bf16_t*)(w + ( 4u<<20));             // 128 KB
    bf16_t* Wob  = (bf16_t*)(w + ( 4u<<20) + (1u<<18));  // 128 KB
    bf16_t* W1b  = (bf16_t*)(w + ( 5u<<20));             // 512 KB
    bf16_t* W2b  = (bf16_t*)(w + ( 6u<<20));             // 512 KB
    bf16_t* srcb = (bf16_t*)(w + ( 8u<<20));             // 8 MB (alive thru ln1)
    bf16_t* y2   = (bf16_t*)(w + ( 8u<<20));             // aliases srcb (after ln1)
    bf16_t* vtg  = (bf16_t*)(w + (16u<<20));             // 8 MB vfrag (dead after attn)
    bf16_t* y1   = (bf16_t*)(w + (16u<<20));             // aliases vtg
    bf16_t* ctx  = (bf16_t*)(w + (24u<<20));             // 8 MB (dead after Wo-gemm)
    bf16_t* xws  = (bf16_t*)(w + (24u<<20));             // aliases ctx (after Wo-gemm)
    bf16_t* hws  = (bf16_t*)(w + (32u<<20));             // 32 MB

    prep_kernel<<<dim3(4800), 256, 0, stream>>>(
        src, srcb, Wv, Wvb, Wo, Wob, W1, W1b, W2, W2b,
        pos, Wpos, bpos, ls, xkb, xqb);

    // v = src @ Wv^T + bv  -> fragment-ordered store vfrag[b][eb][k16][lane][8]
    gemm_t<3, bf16_t><<<dim3(BS/64, EN/64), 256, 0, stream>>>(
        srcb, Wvb, bv, (bf16_t*)nullptr, vtg, EN, EN);
    // ctx = softmax(os*exp(-0.5*d2)) @ v
    attn_kernel<<<dim3(256), 512, 0, stream>>>(xkb, xqb, vtg, os, ctx);
    // y1 = ctx @ Wo^T + bo ; x = LN1(y1 + src)
    gemm_t<0, bf16_t><<<dim3(BS/64, EN/64), 256, 0, stream>>>(
        ctx, Wob, bo, y1, (bf16_t*)nullptr, EN, EN);
    ln_kernel<bf16_t, bf16_t><<<dim3(BS/32), 256, 0, stream>>>(y1, srcb, g1, be1, xws);
    // h = relu(x @ W1^T + b1)
    gemm_t<1, bf16_t><<<dim3(BS/64, FN/64), 256, 0, stream>>>(
        xws, W1b, b1, hws, (bf16_t*)nullptr, FN, EN);
    // y2 = h @ W2^T + b2 ; out = LN2(y2 + x) -> fp32
    gemm_t<0, bf16_t><<<dim3(BS/64, EN/64), 256, 0, stream>>>(
        hws, W2b, b2, y2, (bf16_t*)nullptr, EN, FN);
    ln_kernel<float, bf16_t><<<dim3(BS/32), 256, 0, stream>>>(y2, xws, g2, be2, (float*)d_out);
}